// Round 2
// baseline (534.789 us; speedup 1.0000x reference)
//
#include <hip/hip_runtime.h>
#include <math.h>

// Problem constants (match reference)
#define B_N 4096
#define L_N 1000
#define M_N 16
#define K_N 20
#define NF  48          // 16 filters x {w1, w2, qw_loc}
#define TVALID 981      // L - K + 1

// Workspace layout (float offsets)
#define WS_W    0       // 48*80 = 3840 floats: [0:16)=w1, [16:32)=w2, [32:48)=qw_loc
#define WS_KL2  3840    // 2 * KL sum
#define WS_S    3841    // s = 1/softplus(gen_scale)
#define WS_S1   3842    // accumulator: sum_b (A[b] - sum_m z*g0)
#define WS_ZSUM 3843    // [16] sum_b z[b,m]
#define WS_BSUM 3859    // [16] sum_b (y*clip(log p2) + (1-y)*clip(log(1-p2)))

static __device__ __forceinline__ float softplus_f(float x) {
    // jax.nn.softplus = logaddexp(x, 0) = max(x,0) + log1p(exp(-|x|))
    return fmaxf(x, 0.f) + log1pf(expf(-fabsf(x)));
}

// ---------------- Kernel 1: derive weights, KL, s; zero accumulators ----------------
__global__ void prep_kernel(const float* __restrict__ qw_loc,
                            const float* __restrict__ qw_scale_raw,
                            const float* __restrict__ gen_scale,
                            const float* __restrict__ eps1,
                            const float* __restrict__ eps2,
                            float* __restrict__ wsf) {
    int tid = threadIdx.x;
    double kl = 0.0;
    for (int i = tid; i < M_N * 80; i += 256) {
        float loc = qw_loc[i];
        float raw = qw_scale_raw[i];
        float qs  = softplus_f(raw);
        wsf[WS_W + i]            = loc + qs * eps1[i];   // w1
        wsf[WS_W + 1280 + i]     = loc + qs * eps2[i];   // w2
        wsf[WS_W + 2560 + i]     = loc;                  // qw_loc
        float dl = loc + 0.01f;  // loc - PRIOR_LOC
        kl += (double)(logf(0.001f / qs) + (qs * qs + dl * dl) / 2e-6f - 0.5f);
    }
    __shared__ double red[256];
    red[tid] = kl;
    __syncthreads();
    for (int s = 128; s > 0; s >>= 1) {
        if (tid < s) red[tid] += red[tid + s];
        __syncthreads();
    }
    if (tid == 0) {
        wsf[WS_KL2] = (float)(2.0 * red[0]);
        wsf[WS_S]   = 1.0f / softplus_f(gen_scale[0]);
        wsf[WS_S1]  = 0.f;
        for (int m = 0; m < M_N; ++m) {
            wsf[WS_ZSUM + m] = 0.f;
            wsf[WS_BSUM + m] = 0.f;
        }
    }
}

// ---------------- Kernel 2: per-sample conv-max for 48 filters + epilogue ----------------
// wts: weight region of ws (read-only here). red: accumulator region (atomics).
__global__ __launch_bounds__(256) void conv_kernel(const float* __restrict__ x,
                                                   const float* __restrict__ y,
                                                   const float* __restrict__ wts,
                                                   float* __restrict__ red,
                                                   float* __restrict__ out) {
    __shared__ __align__(16) float xs[4][1048];   // 4 x (1000 + pad) floats
    __shared__ float maxs[NF];

    const int b   = blockIdx.x;
    const int tid = threadIdx.x;

    // Stage x[b] (4 rows of 1000 floats) via float4
    const float4* xg4 = (const float4*)(x + (size_t)b * 4000);
    for (int i = tid; i < 1000; i += 256) {
        float4 v = xg4[i];
        int c = i / 250, off = (i % 250) * 4;
        *(float4*)&xs[c][off] = v;
    }
    if (tid < 192) {  // zero-pad tails (scores there are masked from max)
        int c = tid / 48, p = 1000 + (tid % 48);
        xs[c][p] = 0.f;
    }
    __syncthreads();

    const int wave = tid >> 6, lane = tid & 63;
    const int mbase = wave * 12;   // each wave owns 12 filters over all positions

    // Wave-uniform weight base -> SGPR; loads from it should scalarize (s_load)
    const int mbase_u = __builtin_amdgcn_readfirstlane(mbase);
    const float* __restrict__ wq = wts + mbase_u * 80;

    float vmax[12];
#pragma unroll
    for (int f = 0; f < 12; ++f) vmax[f] = -INFINITY;

#pragma unroll
    for (int p = 0; p < 2; ++p) {
        const int t0 = p * 512 + lane * 8;     // 8 consecutive positions per lane
        float acc[12][8];
#pragma unroll
        for (int f = 0; f < 12; ++f)
#pragma unroll
            for (int j = 0; j < 8; ++j) acc[f][j] = 0.f;

        for (int c = 0; c < 4; ++c) {
            float win[28];
#pragma unroll
            for (int q = 0; q < 7; ++q) {
                float4 v = *(const float4*)&xs[c][t0 + q * 4];
                win[q * 4 + 0] = v.x; win[q * 4 + 1] = v.y;
                win[q * 4 + 2] = v.z; win[q * 4 + 3] = v.w;
            }
            const float* __restrict__ wc = wq + c * 20;
#pragma unroll
            for (int f = 0; f < 12; ++f) {
#pragma unroll
                for (int k4 = 0; k4 < 5; ++k4) {
                    // wave-uniform address -> s_load_dwordx4; FMA uses SGPR operand
                    float4 wv = *(const float4*)(wc + f * 80 + k4 * 4);
#define STEP(KK, WC)                                                \
                    acc[f][0] = fmaf(win[(KK) + 0], WC, acc[f][0]); \
                    acc[f][1] = fmaf(win[(KK) + 1], WC, acc[f][1]); \
                    acc[f][2] = fmaf(win[(KK) + 2], WC, acc[f][2]); \
                    acc[f][3] = fmaf(win[(KK) + 3], WC, acc[f][3]); \
                    acc[f][4] = fmaf(win[(KK) + 4], WC, acc[f][4]); \
                    acc[f][5] = fmaf(win[(KK) + 5], WC, acc[f][5]); \
                    acc[f][6] = fmaf(win[(KK) + 6], WC, acc[f][6]); \
                    acc[f][7] = fmaf(win[(KK) + 7], WC, acc[f][7]);
                    STEP(k4 * 4 + 0, wv.x)
                    STEP(k4 * 4 + 1, wv.y)
                    STEP(k4 * 4 + 2, wv.z)
                    STEP(k4 * 4 + 3, wv.w)
#undef STEP
                }
            }
        }
#pragma unroll
        for (int f = 0; f < 12; ++f)
#pragma unroll
            for (int j = 0; j < 8; ++j)
                if (t0 + j < TVALID) vmax[f] = fmaxf(vmax[f], acc[f][j]);
    }

    // wave-level max reduction (wave owns the filter entirely)
#pragma unroll
    for (int f = 0; f < 12; ++f) {
        float v = vmax[f];
        for (int off = 32; off > 0; off >>= 1)
            v = fmaxf(v, __shfl_xor(v, off, 64));
        if (lane == 0) maxs[mbase + f] = v;
    }
    __syncthreads();

    // ---- epilogue: 16 lanes, one per motif ----
    if (tid < 16) {
        const int m = tid;
        const float s_ = red[WS_S - 3840];   // red points at wsf+3840
        const float yb = y[b];
        const float sc1 = maxs[m], sc2 = maxs[16 + m], sc0 = maxs[32 + m];

        // z from w1 scores
        float p1 = 1.f / (1.f + expf(-sc1));
        float lp = logf(p1) + log1pf(-p1);
        float mx = lp;
#pragma unroll
        for (int o = 8; o; o >>= 1) mx = fmaxf(mx, __shfl_xor(mx, o, 16));
        float e = expf(lp - mx);
        float se = e;
#pragma unroll
        for (int o = 8; o; o >>= 1) se += __shfl_xor(se, o, 16);
        float z = e / se;
        float Aterm = z * logf(1e-20f + z);

        // generative term from w2 scores
        float p2 = 1.f / (1.f + expf(-sc2));
        float g0 = -logf(1e-16f + powf(1e-16f + p2, s_) + powf(1.0f - p2, s_));
        float Cterm = z * g0;
        // BCE pieces (reference uses plain log(1-p), clamped at -100)
        float bterm = yb * fmaxf(logf(p2), -100.f)
                    + (1.f - yb) * fmaxf(logf(1.f - p2), -100.f);

        float AC = Aterm - Cterm;
#pragma unroll
        for (int o = 8; o; o >>= 1) AC += __shfl_xor(AC, o, 16);

        atomicAdd(&red[WS_ZSUM - 3840 + m], z);
        atomicAdd(&red[WS_BSUM - 3840 + m], bterm);

        // predict: argmax_m of lp0 (softmax is monotone), first-index ties
        float p0 = 1.f / (1.f + expf(-sc0));
        float lp0 = logf(p0) + log1pf(-p0);
        float best = lp0; int bidx = m;
#pragma unroll
        for (int o = 8; o; o >>= 1) {
            float ov = __shfl_xor(best, o, 16);
            int   oi = __shfl_xor(bidx, o, 16);
            if (ov > best || (ov == best && oi < bidx)) { best = ov; bidx = oi; }
        }
        if (m == 0) {
            atomicAdd(&red[WS_S1 - 3840], AC);
            out[1 + b] = 1.f / (1.f + expf(-maxs[32 + bidx]));
        }
    }
}

// ---------------- Kernel 3: assemble loss ----------------
__global__ void finish_kernel(const float* __restrict__ wsf, float* __restrict__ out) {
    int tid = threadIdx.x;
    if (tid < 16) {
        float t = wsf[WS_ZSUM + tid] * wsf[WS_BSUM + tid];
#pragma unroll
        for (int o = 8; o; o >>= 1) t += __shfl_xor(t, o, 16);
        if (tid == 0) {
            float s_ = wsf[WS_S];
            // loss = S1/B + 2KL + s * sum_m (zsum/B)*(-bsum/B)
            float loss = wsf[WS_S1] / 4096.0f + wsf[WS_KL2]
                       - s_ * (t / (4096.0f * 4096.0f));
            out[0] = loss;
        }
    }
}

extern "C" void kernel_launch(void* const* d_in, const int* in_sizes, int n_in,
                              void* d_out, int out_size, void* d_ws, size_t ws_size,
                              hipStream_t stream) {
    const float* x            = (const float*)d_in[0];
    const float* y            = (const float*)d_in[1];
    const float* qw_loc       = (const float*)d_in[2];
    const float* qw_scale_raw = (const float*)d_in[3];
    const float* gen_scale    = (const float*)d_in[4];
    const float* eps1         = (const float*)d_in[5];
    const float* eps2         = (const float*)d_in[6];
    float* out = (float*)d_out;
    float* wsf = (float*)d_ws;

    prep_kernel<<<1, 256, 0, stream>>>(qw_loc, qw_scale_raw, gen_scale, eps1, eps2, wsf);
    conv_kernel<<<B_N, 256, 0, stream>>>(x, y, wsf + WS_W, wsf + 3840, out);
    finish_kernel<<<1, 64, 0, stream>>>(wsf, out);
}

// Round 3
// 389.822 us; speedup vs baseline: 1.3719x; 1.3719x over previous
//
#include <hip/hip_runtime.h>
#include <math.h>

// Problem constants
#define B_N 4096
#define L_N 1000
#define M_N 16
#define K_N 20
#define TVALID 981

typedef __bf16 bf16x8 __attribute__((ext_vector_type(8)));
typedef float f32x4 __attribute__((ext_vector_type(4)));

// ws layout (32-bit slots)
// B-fragment dwords: pair p in [0,7): p0=(w1,s1) p1=(w1,s2) p2=(w2,s1) p3=(w2,s2)
//                    p4=(loc,s1) p5=(loc,s2) p6=(loc,s3)
// dword index = ((p*4 + c)*64 + lane)*4 + q   -> 7*4*64*4 = 7168 dwords
#define WS_FRAGS 0
#define WS_KL2   7168
#define WS_S     7169
#define WS_S1    7170
#define WS_ZSUM  7171   // 16
#define WS_BSUM  7187   // 16

static __device__ __forceinline__ float softplus_f(float x) {
    return fmaxf(x, 0.f) + log1pf(expf(-fabsf(x)));
}

static __device__ __forceinline__ uint32_t pk2(__bf16 a, __bf16 b) {
    return (uint32_t)__builtin_bit_cast(unsigned short, a) |
           ((uint32_t)__builtin_bit_cast(unsigned short, b) << 16);
}

static __device__ __forceinline__ bf16x8 FR(uint32_t d0, uint32_t d1, uint32_t d2, uint32_t d3) {
    union { uint32_t u[4]; bf16x8 v; } t;
    t.u[0] = d0; t.u[1] = d1; t.u[2] = d2; t.u[3] = d3;
    return t.v;
}

static __device__ __forceinline__ uint32_t ALGN(uint32_t hi, uint32_t lo) {
    // {out.lo16 = lo.hi16, out.hi16 = hi.lo16} : bf16 pair starting at odd element
    return __builtin_amdgcn_alignbit(hi, lo, 16);
}

static __device__ __forceinline__ f32x4 MF(bf16x8 a, const uint32_t* bq, f32x4 c) {
    union { uint32_t u[4]; bf16x8 v; } b;
    b.u[0] = bq[0]; b.u[1] = bq[1]; b.u[2] = bq[2]; b.u[3] = bq[3];
    return __builtin_amdgcn_mfma_f32_16x16x32_bf16(a, b.v, c, 0, 0, 0);
}

// ---------------- Kernel 1: KL, s, accum zero, B-fragment precompute ----------------
__global__ void prep_kernel(const float* __restrict__ qw_loc,
                            const float* __restrict__ qw_scale_raw,
                            const float* __restrict__ gen_scale,
                            const float* __restrict__ eps1,
                            const float* __restrict__ eps2,
                            float* __restrict__ wsf) {
    int tid = threadIdx.x;
    double kl = 0.0;
    for (int i = tid; i < M_N * 80; i += 256) {
        float loc = qw_loc[i];
        float qs  = softplus_f(qw_scale_raw[i]);
        float dl  = loc + 0.01f;
        kl += (double)(logf(0.001f / qs) + (qs * qs + dl * dl) / 2e-6f - 0.5f);
    }
    __shared__ double red[256];
    red[tid] = kl;
    __syncthreads();
    for (int s = 128; s > 0; s >>= 1) {
        if (tid < s) red[tid] += red[tid + s];
        __syncthreads();
    }
    if (tid == 0) {
        wsf[WS_KL2] = (float)(2.0 * red[0]);
        wsf[WS_S]   = 1.0f / softplus_f(gen_scale[0]);
        wsf[WS_S1]  = 0.f;
        for (int m = 0; m < M_N; ++m) {
            wsf[WS_ZSUM + m] = 0.f;
            wsf[WS_BSUM + m] = 0.f;
        }
    }

    // B-fragments: 7 (var,split) pairs x 4 c x 64 lanes, 4 dwords each.
    uint32_t* wsu = (uint32_t*)wsf;
    for (int idx = tid; idx < 1792; idx += 256) {
        int lane = idx & 63;
        int c    = (idx >> 6) & 3;
        int p    = idx >> 8;                  // 0..6
        int var, sp;                          // var: 0=w1(eps1) 1=w2(eps2) 2=loc
        if (p < 2)      { var = 0; sp = p; }
        else if (p < 4) { var = 1; sp = p - 2; }
        else            { var = 2; sp = p - 4; }
        int n = lane & 15, h = lane >> 4;
        uint32_t q4[4];
#pragma unroll
        for (int q = 0; q < 4; ++q) {
            unsigned short es[2];
#pragma unroll
            for (int e2 = 0; e2 < 2; ++e2) {
                int k = 8 * h + 2 * q + e2;
                unsigned short u = 0;
                if (k < K_N) {
                    int j = n * 80 + c * 20 + k;
                    float w = qw_loc[j];
                    if (var != 2) {
                        float qs = softplus_f(qw_scale_raw[j]);
                        w += qs * (var == 0 ? eps1[j] : eps2[j]);
                    }
                    __bf16 b1 = (__bf16)w;
                    float r1 = w - (float)b1;
                    __bf16 b2 = (__bf16)r1;
                    float r2 = r1 - (float)b2;
                    __bf16 b3 = (__bf16)r2;
                    __bf16 sel = (sp == 0) ? b1 : ((sp == 1) ? b2 : b3);
                    u = __builtin_bit_cast(unsigned short, sel);
                }
                es[e2] = u;
            }
            q4[q] = (uint32_t)es[0] | ((uint32_t)es[1] << 16);
        }
        int base = ((p * 4 + c) * 64 + lane) * 4;
#pragma unroll
        for (int q = 0; q < 4; ++q) wsu[WS_FRAGS + base + q] = q4[q];
    }
}

// ---------------- Kernel 2: MFMA conv-max, 2 samples/block ----------------
__global__ __launch_bounds__(256, 3) void conv_kernel(const float* __restrict__ x,
                                                      const float* __restrict__ y,
                                                      const float* __restrict__ wsf,
                                                      float* __restrict__ red,
                                                      float* __restrict__ out) {
    __shared__ uint32_t xls[2][3][4][512];   // [sample][split][c][dword] bf16x2 packed
    __shared__ float maxs[2][48];

    const int tid  = threadIdx.x;
    const int bid  = blockIdx.x;
    const int wave = tid >> 6, lane = tid & 63;
    const int samp = wave >> 1, role = wave & 1;   // role0: w1+w2, role1: loc
    const int r = lane & 15, h = lane >> 4;
    const int ldw = r + 4 * h;                     // lane dword offset into window

    // B-fragment loads (global, independent of LDS staging)
    const uint4* fg = (const uint4*)((const uint32_t*)wsf + WS_FRAGS);
    uint32_t Bf[16][4];
    if (role == 0) {
#pragma unroll
        for (int f = 0; f < 16; ++f) {
            uint4 t = fg[f * 64 + lane];
            Bf[f][0] = t.x; Bf[f][1] = t.y; Bf[f][2] = t.z; Bf[f][3] = t.w;
        }
    } else {
#pragma unroll
        for (int f = 0; f < 12; ++f) {
            uint4 t = fg[(16 + f) * 64 + lane];
            Bf[f][0] = t.x; Bf[f][1] = t.y; Bf[f][2] = t.z; Bf[f][3] = t.w;
        }
    }

    // Stage x splits for 2 samples: packed bf16 pairs per dword
    for (int s2 = 0; s2 < 2; ++s2) {
        const float2* xg = (const float2*)(x + (size_t)(2 * bid + s2) * 4000);
        for (int i = tid; i < 2000; i += 256) {
            int c = i / 500, dw = i % 500;
            float2 v = xg[c * 500 + dw];
            __bf16 a1 = (__bf16)v.x; float ra = v.x - (float)a1;
            __bf16 a2 = (__bf16)ra;  ra -= (float)a2;
            __bf16 a3 = (__bf16)ra;
            __bf16 b1 = (__bf16)v.y; float rb = v.y - (float)b1;
            __bf16 b2 = (__bf16)rb;  rb -= (float)b2;
            __bf16 b3 = (__bf16)rb;
            xls[s2][0][c][dw] = pk2(a1, b1);
            xls[s2][1][c][dw] = pk2(a2, b2);
            xls[s2][2][c][dw] = pk2(a3, b3);
        }
    }
    for (int i = tid; i < 288; i += 256) {       // zero pad dwords 500..511
        int s2 = i / 144, rem = i % 144;
        int sp = rem / 48, c = (rem / 12) & 3, dw = 500 + rem % 12;
        xls[s2][sp][c][dw] = 0;
    }
    __syncthreads();

    const f32x4 Z = {0.f, 0.f, 0.f, 0.f};

    if (role == 0) {
        // ---- vars w1 (nt0) and w2 (nt1), 2x2 split, 3 products each ----
        f32x4 vm[4];                              // nt0e, nt0o, nt1e, nt1o
#pragma unroll
        for (int t = 0; t < 4; ++t) { vm[t][0]=-INFINITY; vm[t][1]=-INFINITY; vm[t][2]=-INFINITY; vm[t][3]=-INFINITY; }
        for (int i = 0; i < 31; ++i) {
            const int t0h = 16 * i;
            f32x4 acc[4] = {Z, Z, Z, Z};
#pragma unroll
            for (int c = 0; c < 4; ++c) {
                const uint32_t* p1 = &xls[samp][0][c][t0h + ldw];
                uint32_t a0=p1[0], a1=p1[1], a2=p1[2], a3=p1[3], a4=p1[4];
                const uint32_t* p2 = &xls[samp][1][c][t0h + ldw];
                uint32_t b0=p2[0], b1=p2[1], b2=p2[2], b3=p2[3], b4=p2[4];
                bf16x8 A1e = FR(a0, a1, a2, a3);
                bf16x8 A1o = FR(ALGN(a1,a0), ALGN(a2,a1), ALGN(a3,a2), ALGN(a4,a3));
                bf16x8 A2e = FR(b0, b1, b2, b3);
                bf16x8 A2o = FR(ALGN(b1,b0), ALGN(b2,b1), ALGN(b3,b2), ALGN(b4,b3));
                acc[0] = MF(A1e, Bf[c],      acc[0]);  acc[1] = MF(A1o, Bf[c],      acc[1]);
                acc[2] = MF(A1e, Bf[8 + c],  acc[2]);  acc[3] = MF(A1o, Bf[8 + c],  acc[3]);
                acc[0] = MF(A1e, Bf[4 + c],  acc[0]);  acc[1] = MF(A1o, Bf[4 + c],  acc[1]);
                acc[2] = MF(A1e, Bf[12 + c], acc[2]);  acc[3] = MF(A1o, Bf[12 + c], acc[3]);
                acc[0] = MF(A2e, Bf[c],      acc[0]);  acc[1] = MF(A2o, Bf[c],      acc[1]);
                acc[2] = MF(A2e, Bf[8 + c],  acc[2]);  acc[3] = MF(A2o, Bf[8 + c],  acc[3]);
            }
            if (i < 30) {
#pragma unroll
                for (int t = 0; t < 4; ++t)
#pragma unroll
                    for (int q = 0; q < 4; ++q) vm[t][q] = fmaxf(vm[t][q], acc[t][q]);
            } else {
#pragma unroll
                for (int q = 0; q < 4; ++q) {
                    int rowq = 4 * h + q;
                    vm[0][q] = fmaxf(vm[0][q], rowq <= 10 ? acc[0][q] : -INFINITY);
                    vm[1][q] = fmaxf(vm[1][q], rowq <=  9 ? acc[1][q] : -INFINITY);
                    vm[2][q] = fmaxf(vm[2][q], rowq <= 10 ? acc[2][q] : -INFINITY);
                    vm[3][q] = fmaxf(vm[3][q], rowq <=  9 ? acc[3][q] : -INFINITY);
                }
            }
        }
        float m0 = fmaxf(fmaxf(fmaxf(vm[0][0], vm[0][1]), fmaxf(vm[0][2], vm[0][3])),
                         fmaxf(fmaxf(vm[1][0], vm[1][1]), fmaxf(vm[1][2], vm[1][3])));
        m0 = fmaxf(m0, __shfl_xor(m0, 16, 64));
        m0 = fmaxf(m0, __shfl_xor(m0, 32, 64));
        float m1 = fmaxf(fmaxf(fmaxf(vm[2][0], vm[2][1]), fmaxf(vm[2][2], vm[2][3])),
                         fmaxf(fmaxf(vm[3][0], vm[3][1]), fmaxf(vm[3][2], vm[3][3])));
        m1 = fmaxf(m1, __shfl_xor(m1, 16, 64));
        m1 = fmaxf(m1, __shfl_xor(m1, 32, 64));
        if (lane < 16) { maxs[samp][lane] = m0; maxs[samp][16 + lane] = m1; }
    } else {
        // ---- var loc (nt2), 3x3 split, 6 products ----
        f32x4 vm[2];
#pragma unroll
        for (int t = 0; t < 2; ++t) { vm[t][0]=-INFINITY; vm[t][1]=-INFINITY; vm[t][2]=-INFINITY; vm[t][3]=-INFINITY; }
        for (int i = 0; i < 31; ++i) {
            const int t0h = 16 * i;
            f32x4 acc[2] = {Z, Z};
#pragma unroll
            for (int c = 0; c < 4; ++c) {
                const uint32_t* p1 = &xls[samp][0][c][t0h + ldw];
                uint32_t a0=p1[0], a1=p1[1], a2=p1[2], a3=p1[3], a4=p1[4];
                const uint32_t* p2 = &xls[samp][1][c][t0h + ldw];
                uint32_t b0=p2[0], b1=p2[1], b2=p2[2], b3=p2[3], b4=p2[4];
                const uint32_t* p3 = &xls[samp][2][c][t0h + ldw];
                uint32_t c0=p3[0], c1=p3[1], c2=p3[2], c3=p3[3], c4=p3[4];
                bf16x8 A1e = FR(a0, a1, a2, a3);
                bf16x8 A1o = FR(ALGN(a1,a0), ALGN(a2,a1), ALGN(a3,a2), ALGN(a4,a3));
                bf16x8 A2e = FR(b0, b1, b2, b3);
                bf16x8 A2o = FR(ALGN(b1,b0), ALGN(b2,b1), ALGN(b3,b2), ALGN(b4,b3));
                bf16x8 A3e = FR(c0, c1, c2, c3);
                bf16x8 A3o = FR(ALGN(c1,c0), ALGN(c2,c1), ALGN(c3,c2), ALGN(c4,c3));
                acc[0] = MF(A1e, Bf[c],     acc[0]);  acc[1] = MF(A1o, Bf[c],     acc[1]);
                acc[0] = MF(A1e, Bf[4 + c], acc[0]);  acc[1] = MF(A1o, Bf[4 + c], acc[1]);
                acc[0] = MF(A2e, Bf[c],     acc[0]);  acc[1] = MF(A2o, Bf[c],     acc[1]);
                acc[0] = MF(A1e, Bf[8 + c], acc[0]);  acc[1] = MF(A1o, Bf[8 + c], acc[1]);
                acc[0] = MF(A2e, Bf[4 + c], acc[0]);  acc[1] = MF(A2o, Bf[4 + c], acc[1]);
                acc[0] = MF(A3e, Bf[c],     acc[0]);  acc[1] = MF(A3o, Bf[c],     acc[1]);
            }
            if (i < 30) {
#pragma unroll
                for (int t = 0; t < 2; ++t)
#pragma unroll
                    for (int q = 0; q < 4; ++q) vm[t][q] = fmaxf(vm[t][q], acc[t][q]);
            } else {
#pragma unroll
                for (int q = 0; q < 4; ++q) {
                    int rowq = 4 * h + q;
                    vm[0][q] = fmaxf(vm[0][q], rowq <= 10 ? acc[0][q] : -INFINITY);
                    vm[1][q] = fmaxf(vm[1][q], rowq <=  9 ? acc[1][q] : -INFINITY);
                }
            }
        }
        float m2 = fmaxf(fmaxf(fmaxf(vm[0][0], vm[0][1]), fmaxf(vm[0][2], vm[0][3])),
                         fmaxf(fmaxf(vm[1][0], vm[1][1]), fmaxf(vm[1][2], vm[1][3])));
        m2 = fmaxf(m2, __shfl_xor(m2, 16, 64));
        m2 = fmaxf(m2, __shfl_xor(m2, 32, 64));
        if (lane < 16) maxs[samp][32 + lane] = m2;
    }
    __syncthreads();

    // ---- epilogue: lanes 0-15 -> sample0, 16-31 -> sample1 ----
    if (tid < 32) {
        const int se = tid >> 4, m = tid & 15;
        const int b = 2 * bid + se;
        const float s_ = red[WS_S - WS_KL2];      // red points at wsf+WS_KL2
        const float yb = y[b];
        const float sc1 = maxs[se][m], sc2 = maxs[se][16 + m], sc0 = maxs[se][32 + m];

        float p1 = 1.f / (1.f + expf(-sc1));
        float lp = logf(p1) + log1pf(-p1);
        float mx = lp;
#pragma unroll
        for (int o = 8; o; o >>= 1) mx = fmaxf(mx, __shfl_xor(mx, o, 16));
        float e = expf(lp - mx);
        float se_ = e;
#pragma unroll
        for (int o = 8; o; o >>= 1) se_ += __shfl_xor(se_, o, 16);
        float z = e / se_;
        float Aterm = z * logf(1e-20f + z);

        float p2 = 1.f / (1.f + expf(-sc2));
        float g0 = -logf(1e-16f + powf(1e-16f + p2, s_) + powf(1.0f - p2, s_));
        float Cterm = z * g0;
        float bterm = yb * fmaxf(logf(p2), -100.f)
                    + (1.f - yb) * fmaxf(logf(1.f - p2), -100.f);

        float AC = Aterm - Cterm;
#pragma unroll
        for (int o = 8; o; o >>= 1) AC += __shfl_xor(AC, o, 16);

        atomicAdd(&red[WS_ZSUM - WS_KL2 + m], z);
        atomicAdd(&red[WS_BSUM - WS_KL2 + m], bterm);

        float p0 = 1.f / (1.f + expf(-sc0));
        float lp0 = logf(p0) + log1pf(-p0);
        float best = lp0; int bidx = m;
#pragma unroll
        for (int o = 8; o; o >>= 1) {
            float ov = __shfl_xor(best, o, 16);
            int   oi = __shfl_xor(bidx, o, 16);
            if (ov > best || (ov == best && oi < bidx)) { best = ov; bidx = oi; }
        }
        if (m == 0) {
            atomicAdd(&red[WS_S1 - WS_KL2], AC);
            out[1 + b] = 1.f / (1.f + expf(-maxs[se][32 + bidx]));
        }
    }
}

// ---------------- Kernel 3: assemble loss ----------------
__global__ void finish_kernel(const float* __restrict__ wsf, float* __restrict__ out) {
    int tid = threadIdx.x;
    if (tid < 16) {
        float t = wsf[WS_ZSUM + tid] * wsf[WS_BSUM + tid];
#pragma unroll
        for (int o = 8; o; o >>= 1) t += __shfl_xor(t, o, 16);
        if (tid == 0) {
            float s_ = wsf[WS_S];
            float loss = wsf[WS_S1] / 4096.0f + wsf[WS_KL2]
                       - s_ * (t / (4096.0f * 4096.0f));
            out[0] = loss;
        }
    }
}

extern "C" void kernel_launch(void* const* d_in, const int* in_sizes, int n_in,
                              void* d_out, int out_size, void* d_ws, size_t ws_size,
                              hipStream_t stream) {
    const float* x            = (const float*)d_in[0];
    const float* y            = (const float*)d_in[1];
    const float* qw_loc       = (const float*)d_in[2];
    const float* qw_scale_raw = (const float*)d_in[3];
    const float* gen_scale    = (const float*)d_in[4];
    const float* eps1         = (const float*)d_in[5];
    const float* eps2         = (const float*)d_in[6];
    float* out = (float*)d_out;
    float* wsf = (float*)d_ws;

    prep_kernel<<<1, 256, 0, stream>>>(qw_loc, qw_scale_raw, gen_scale, eps1, eps2, wsf);
    conv_kernel<<<B_N / 2, 256, 0, stream>>>(x, y, wsf, wsf + WS_KL2, out);
    finish_kernel<<<1, 64, 0, stream>>>(wsf, out);
}

// Round 4
// 282.776 us; speedup vs baseline: 1.8912x; 1.3786x over previous
//
#include <hip/hip_runtime.h>
#include <math.h>

// Problem constants
#define B_N 4096
#define TVALID 981

typedef _Float16 f16x8 __attribute__((ext_vector_type(8)));
typedef float f32x16 __attribute__((ext_vector_type(16)));
typedef unsigned int u32x2 __attribute__((ext_vector_type(2)));

// ws layout (dword offsets):
// [0, 3840): B fragments. set = grp*5 + step, grp0=[w1s1|w2s1], grp1=[w1s2|w2s2],
//            grp2=[loc s1|loc s2]; dword idx = (set*64 + lane)*4 + q
// [3840+0]=s, [+1]=S1, [+2..18)=ZSUM, [+18..34)=BSUM
#define WS_FRAG 0
#define WS_RED  3840

static __device__ __forceinline__ float softplus_f(float x) {
    // jax.nn.softplus = max(x,0) + log1p(exp(-|x|))
    return fmaxf(x, 0.f) + log1pf(expf(-fabsf(x)));
}
static __device__ __forceinline__ uint32_t pkh(_Float16 a, _Float16 b) {
    return (uint32_t)__builtin_bit_cast(unsigned short, a)
         | ((uint32_t)__builtin_bit_cast(unsigned short, b) << 16);
}
static __device__ __forceinline__ f16x8 mkfrag(u32x2 lo, u32x2 hi) {
    union { uint32_t u[4]; f16x8 v; } t;
    t.u[0] = lo.x; t.u[1] = lo.y; t.u[2] = hi.x; t.u[3] = hi.y;
    return t.v;
}
static __device__ __forceinline__ f16x8 mkbfrag(const uint32_t* q) {
    union { uint32_t u[4]; f16x8 v; } t;
    t.u[0] = q[0]; t.u[1] = q[1]; t.u[2] = q[2]; t.u[3] = q[3];
    return t.v;
}

// ---------------- Kernel 1: B-fragment precompute (f16 2-split) + accum init ----------------
__global__ void prep_kernel(const float* __restrict__ qw_loc,
                            const float* __restrict__ qw_scale_raw,
                            const float* __restrict__ gen_scale,
                            const float* __restrict__ eps1,
                            const float* __restrict__ eps2,
                            float* __restrict__ wsf) {
    int g = blockIdx.x * 256 + threadIdx.x;
    if (g == 960) {
        float* red = wsf + WS_RED;
        red[0] = 1.0f / softplus_f(gen_scale[0]);
        red[1] = 0.f;
        for (int i = 0; i < 32; ++i) red[2 + i] = 0.f;
    }
    if (g >= 960) return;
    const int lane = g & 63, set = g >> 6;      // set = grp*5 + s
    const int grp = set / 5, s = set - grp * 5;
    const int h = lane >> 5, n = lane & 31, f = n & 15;
    const int var = (grp == 2) ? 2 : (n < 16 ? 0 : 1);   // 0=w1 1=w2 2=loc
    const int spl = (grp == 2) ? (n < 16 ? 0 : 1) : grp; // 0=f16(w), 1=residual
    uint32_t d[4];
#pragma unroll
    for (int q = 0; q < 4; ++q) {
        unsigned short es[2];
#pragma unroll
        for (int e = 0; e < 2; ++e) {
            int j = 2 * q + e;                  // element 0..7
            int c = j & 3;
            int kk = 4 * s + 2 * h + (j >> 2); // always <= 19
            int idx = f * 80 + c * 20 + kk;
            float w = qw_loc[idx];
            if (var != 2) {
                float qs = softplus_f(qw_scale_raw[idx]);
                w += qs * (var == 0 ? eps1[idx] : eps2[idx]);
            }
            _Float16 h1 = (_Float16)w;
            _Float16 hv = spl ? (_Float16)(w - (float)h1) : h1;
            es[e] = __builtin_bit_cast(unsigned short, hv);
        }
        d[q] = (uint32_t)es[0] | ((uint32_t)es[1] << 16);
    }
    uint4* out4 = (uint4*)((uint32_t*)wsf + WS_FRAG);
    out4[set * 64 + lane] = make_uint4(d[0], d[1], d[2], d[3]);
}

// ---------------- Kernel 2: 32x32x16 f16 MFMA conv-max, 1 sample/block, 2 waves ----------------
__global__ __launch_bounds__(128, 3) void conv_kernel(const float* __restrict__ x,
                                                      const float* __restrict__ y,
                                                      const float* __restrict__ wsf,
                                                      float* __restrict__ red,
                                                      float* __restrict__ out) {
    __shared__ uint32_t xls[2][2048];   // [split][pos*2 + d]: transposed-interleaved f16 pairs
    __shared__ float maxs[2][48];

    const int tid = threadIdx.x, b = blockIdx.x;
    const int lane = tid & 63, wid = tid >> 6;

    // ---- B-fragment loads (global, L2/L3-resident) ----
    uint32_t Bv[15][4];
    const uint4* fg = (const uint4*)((const uint32_t*)wsf + WS_FRAG);
#pragma unroll
    for (int u = 0; u < 15; ++u) {
        uint4 t = fg[u * 64 + lane];
        Bv[u][0] = t.x; Bv[u][1] = t.y; Bv[u][2] = t.z; Bv[u][3] = t.w;
    }

    // ---- stage x: split into f16 hi/lo, transposed xi[pos] = {c0,c1 | c2,c3} ----
    const float* xb = x + (size_t)b * 4000;
#pragma unroll
    for (int j = 0; j < 4; ++j) {
        int p0 = 2 * (tid + 128 * j);           // even position, two positions per unit
        float v[4][2];
        if (p0 < 1000) {
#pragma unroll
            for (int c = 0; c < 4; ++c) {
                float2 t = *(const float2*)(xb + c * 1000 + p0);
                v[c][0] = t.x; v[c][1] = t.y;
            }
        } else {
#pragma unroll
            for (int c = 0; c < 4; ++c) { v[c][0] = 0.f; v[c][1] = 0.f; }
        }
        uint32_t s0[4], s1[4];
#pragma unroll
        for (int e = 0; e < 2; ++e) {
            _Float16 a[4], r[4];
#pragma unroll
            for (int c = 0; c < 4; ++c) {
                a[c] = (_Float16)v[c][e];
                r[c] = (_Float16)(v[c][e] - (float)a[c]);
            }
            s0[2 * e + 0] = pkh(a[0], a[1]); s0[2 * e + 1] = pkh(a[2], a[3]);
            s1[2 * e + 0] = pkh(r[0], r[1]); s1[2 * e + 1] = pkh(r[2], r[3]);
        }
        *(uint4*)&xls[0][4 * (tid + 128 * j)] = make_uint4(s0[0], s0[1], s0[2], s0[3]);
        *(uint4*)&xls[1][4 * (tid + 128 * j)] = make_uint4(s1[0], s1[1], s1[2], s1[3]);
    }
    __syncthreads();

    const int i31 = lane & 31, h = lane >> 5;
    float vmW[16], vmL[16];
#pragma unroll
    for (int e = 0; e < 16; ++e) { vmW[e] = -INFINITY; vmL[e] = -INFINITY; }

    const int t_beg = wid ? 16 : 0, t_end = wid ? 31 : 16;
    for (int tile = t_beg; tile < t_end; ++tile) {
        const int tb = tile * 32;
        f32x16 accW, accL;
#pragma unroll
        for (int e = 0; e < 16; ++e) { accW[e] = 0.f; accL[e] = 0.f; }
#pragma unroll
        for (int s = 0; s < 5; ++s) {
            const int p = tb + i31 + 4 * s + 2 * h;
            u32x2 a0 = *(const u32x2*)&xls[0][2 * p];
            u32x2 a1 = *(const u32x2*)&xls[0][2 * p + 2];
            u32x2 b0 = *(const u32x2*)&xls[1][2 * p];
            u32x2 b1 = *(const u32x2*)&xls[1][2 * p + 2];
            f16x8 A1 = mkfrag(a0, a1);
            f16x8 A2 = mkfrag(b0, b1);
            f16x8 B0 = mkbfrag(Bv[s]);       // [w1 s1 | w2 s1]
            f16x8 B1 = mkbfrag(Bv[5 + s]);   // [w1 s2 | w2 s2]
            f16x8 B2 = mkbfrag(Bv[10 + s]);  // [loc s1 | loc s2]
            accW = __builtin_amdgcn_mfma_f32_32x32x16_f16(A1, B0, accW, 0, 0, 0);
            accL = __builtin_amdgcn_mfma_f32_32x32x16_f16(A1, B2, accL, 0, 0, 0);
            accW = __builtin_amdgcn_mfma_f32_32x32x16_f16(A1, B1, accW, 0, 0, 0);
            accL = __builtin_amdgcn_mfma_f32_32x32x16_f16(A2, B2, accL, 0, 0, 0);
            accW = __builtin_amdgcn_mfma_f32_32x32x16_f16(A2, B0, accW, 0, 0, 0);
        }
        if (tile < 30) {
#pragma unroll
            for (int e = 0; e < 16; ++e) {
                vmW[e] = fmaxf(vmW[e], accW[e]);
                float sum = accL[e] + __shfl_xor(accL[e], 16, 64);
                vmL[e] = fmaxf(vmL[e], sum);
            }
        } else {
#pragma unroll
            for (int e = 0; e < 16; ++e) {
                int row = (e & 3) + 8 * (e >> 2) + 4 * h;
                bool ok = (tb + row) < TVALID;
                vmW[e] = fmaxf(vmW[e], ok ? accW[e] : -INFINITY);
                float sum = accL[e] + __shfl_xor(accL[e], 16, 64);
                vmL[e] = fmaxf(vmL[e], ok ? sum : -INFINITY);
            }
        }
    }

    // per-wave reduce: max over acc slots, then across row-halves (lane^32)
    float mW = vmW[0], mL = vmL[0];
#pragma unroll
    for (int e = 1; e < 16; ++e) { mW = fmaxf(mW, vmW[e]); mL = fmaxf(mL, vmL[e]); }
    mW = fmaxf(mW, __shfl_xor(mW, 32, 64));
    mL = fmaxf(mL, __shfl_xor(mL, 32, 64));
    if (lane < 32) maxs[wid][lane] = mW;        // cols 0-15 = w1, 16-31 = w2
    if (lane < 16) maxs[wid][32 + lane] = mL;   // loc
    __syncthreads();

    // ---- epilogue: 16 lanes, one per motif (same math as validated R2) ----
    if (tid < 16) {
        const int m = tid;
        const float s_ = red[0];
        const float yb = y[b];
        float sc1 = fmaxf(maxs[0][m],      maxs[1][m]);
        float sc2 = fmaxf(maxs[0][16 + m], maxs[1][16 + m]);
        float sc0 = fmaxf(maxs[0][32 + m], maxs[1][32 + m]);

        float p1 = 1.f / (1.f + expf(-sc1));
        float lp = logf(p1) + log1pf(-p1);
        float mx = lp;
#pragma unroll
        for (int o = 8; o; o >>= 1) mx = fmaxf(mx, __shfl_xor(mx, o, 16));
        float e = expf(lp - mx);
        float se_ = e;
#pragma unroll
        for (int o = 8; o; o >>= 1) se_ += __shfl_xor(se_, o, 16);
        float z = e / se_;
        float Aterm = z * logf(1e-20f + z);

        float p2 = 1.f / (1.f + expf(-sc2));
        float g0 = -logf(1e-16f + powf(1e-16f + p2, s_) + powf(1.0f - p2, s_));
        float Cterm = z * g0;
        float bterm = yb * fmaxf(logf(p2), -100.f)
                    + (1.f - yb) * fmaxf(logf(1.f - p2), -100.f);

        float AC = Aterm - Cterm;
#pragma unroll
        for (int o = 8; o; o >>= 1) AC += __shfl_xor(AC, o, 16);

        atomicAdd(&red[2 + m], z);
        atomicAdd(&red[18 + m], bterm);

        float p0 = 1.f / (1.f + expf(-sc0));
        float lp0 = logf(p0) + log1pf(-p0);
        float best = lp0; int bidx = m;
#pragma unroll
        for (int o = 8; o; o >>= 1) {
            float ov = __shfl_xor(best, o, 16);
            int   oi = __shfl_xor(bidx, o, 16);
            if (ov > best || (ov == best && oi < bidx)) { best = ov; bidx = oi; }
        }
        if (m == 0) {
            atomicAdd(&red[1], AC);
            out[1 + b] = 1.f / (1.f + expf(-fmaxf(maxs[0][32 + bidx], maxs[1][32 + bidx])));
        }
    }
}

// ---------------- Kernel 3: KL (moved here) + assemble loss ----------------
__global__ void finish_kernel(const float* __restrict__ qw_loc,
                              const float* __restrict__ qw_scale_raw,
                              const float* __restrict__ wsf,
                              float* __restrict__ out) {
    int tid = threadIdx.x;   // 64 threads
    double kl = 0.0;
    for (int i = tid; i < 1280; i += 64) {
        float loc = qw_loc[i], qs = softplus_f(qw_scale_raw[i]);
        float dl = loc + 0.01f;
        kl += (double)(logf(0.001f / qs) + (qs * qs + dl * dl) / 2e-6f - 0.5f);
    }
#pragma unroll
    for (int o = 32; o; o >>= 1) kl += __shfl_xor(kl, o, 64);
    if (tid == 0) {
        const float* red = wsf + WS_RED;
        float t = 0.f;
        for (int m = 0; m < 16; ++m) t += red[2 + m] * red[18 + m];
        float loss = red[1] / 4096.0f + (float)(2.0 * kl)
                   - red[0] * (t / (4096.0f * 4096.0f));
        out[0] = loss;
    }
}

extern "C" void kernel_launch(void* const* d_in, const int* in_sizes, int n_in,
                              void* d_out, int out_size, void* d_ws, size_t ws_size,
                              hipStream_t stream) {
    const float* x            = (const float*)d_in[0];
    const float* y            = (const float*)d_in[1];
    const float* qw_loc       = (const float*)d_in[2];
    const float* qw_scale_raw = (const float*)d_in[3];
    const float* gen_scale    = (const float*)d_in[4];
    const float* eps1         = (const float*)d_in[5];
    const float* eps2         = (const float*)d_in[6];
    float* out = (float*)d_out;
    float* wsf = (float*)d_ws;

    prep_kernel<<<4, 256, 0, stream>>>(qw_loc, qw_scale_raw, gen_scale, eps1, eps2, wsf);
    conv_kernel<<<B_N, 128, 0, stream>>>(x, y, wsf, wsf + WS_RED, out);
    finish_kernel<<<1, 64, 0, stream>>>(qw_loc, qw_scale_raw, wsf, out);
}

// Round 5
// 270.296 us; speedup vs baseline: 1.9785x; 1.0462x over previous
//
#include <hip/hip_runtime.h>
#include <math.h>

// Problem constants
#define B_N 4096
#define TVALID 981

typedef _Float16 f16x8 __attribute__((ext_vector_type(8)));
typedef float f32x16 __attribute__((ext_vector_type(16)));

// ws layout (dword offsets):
// [0, 5120): B fragments, 20 sets: set = grp*5 + s (s = k-step 0..4)
//   grp0=[w1s1|w2s1]  grp1=[w1s2|w2s2]  grp2=[Ls1|Ls2]  grp3=[Ls2|0]
//   dword idx = (set*64 + lane)*4 + q
// [5120): red block: [0]=s, [1]=S1, [2..18)=ZSUM, [18..34)=BSUM
#define WS_FRAG 0
#define WS_RED  5120

static __device__ __forceinline__ float softplus_f(float x) {
    // jax.nn.softplus = max(x,0) + log1p(exp(-|x|))
    return fmaxf(x, 0.f) + log1pf(expf(-fabsf(x)));
}
static __device__ __forceinline__ uint32_t pkh(_Float16 a, _Float16 b) {
    return (uint32_t)__builtin_bit_cast(unsigned short, a)
         | ((uint32_t)__builtin_bit_cast(unsigned short, b) << 16);
}
static __device__ __forceinline__ f16x8 mkfrag(uint32_t d0, uint32_t d1, uint32_t d2, uint32_t d3) {
    union { uint32_t u[4]; f16x8 v; } t;
    t.u[0] = d0; t.u[1] = d1; t.u[2] = d2; t.u[3] = d3;
    return t.v;
}

// ---------------- Kernel 1: B-fragment precompute (f16 2-split) + accum init ----------------
__global__ void prep_kernel(const float* __restrict__ qw_loc,
                            const float* __restrict__ qw_scale_raw,
                            const float* __restrict__ gen_scale,
                            const float* __restrict__ eps1,
                            const float* __restrict__ eps2,
                            float* __restrict__ wsf) {
    const int g = blockIdx.x * 256 + threadIdx.x;   // 0..1279 (grid = 5*256)
    float* red = wsf + WS_RED;
    if (g == 0) red[0] = 1.0f / softplus_f(gen_scale[0]);
    else if (g < 34) red[g] = 0.f;                  // S1 + 16 zsum + 16 bsum
    if (g >= 1280) return;

    const int lane = g & 63, set = g >> 6;          // set 0..19
    const int grp = set / 5, s = set - grp * 5;
    const int h = lane >> 5, n = lane & 31, f = n & 15;
    int var, spl;                                    // var: 0=w1 1=w2 2=loc 3=zero
    if (grp == 0)      { var = (n < 16) ? 0 : 1; spl = 0; }
    else if (grp == 1) { var = (n < 16) ? 0 : 1; spl = 1; }
    else if (grp == 2) { var = 2;                spl = (n < 16) ? 0 : 1; }
    else               { var = (n < 16) ? 2 : 3; spl = 1; }

    uint32_t d[4];
#pragma unroll
    for (int q = 0; q < 4; ++q) {
        unsigned short es[2];
#pragma unroll
        for (int e = 0; e < 2; ++e) {
            const int j = 2 * q + e;                 // fragment element 0..7
            const int c = j & 3;
            const int kk = 4 * s + 2 * h + (j >> 2); // <= 19
            const int idx = f * 80 + c * 20 + kk;
            float w = 0.f;
            if (var != 3) {
                w = qw_loc[idx];
                if (var < 2) w += softplus_f(qw_scale_raw[idx]) * (var == 0 ? eps1[idx] : eps2[idx]);
            }
            _Float16 h1 = (_Float16)w;
            _Float16 hv = spl ? (_Float16)(w - (float)h1) : h1;
            es[e] = __builtin_bit_cast(unsigned short, hv);
        }
        d[q] = (uint32_t)es[0] | ((uint32_t)es[1] << 16);
    }
    uint4* out4 = (uint4*)((uint32_t*)wsf + WS_FRAG);
    out4[set * 64 + lane] = make_uint4(d[0], d[1], d[2], d[3]);
}

// ---------------- Kernel 2: 32x32x16 f16 MFMA conv-max, 1 sample/block, 4 waves ----------------
__global__ __launch_bounds__(256) void conv_kernel(const float* __restrict__ x,
                                                   const float* __restrict__ y,
                                                   const float* __restrict__ wsf,
                                                   float* __restrict__ red,
                                                   float* __restrict__ out) {
    // packed per-position record: {c01 s0, c23 s0, c01 s1, c23 s1} = 16B, 1024 positions
    __shared__ __align__(16) uint32_t xls[4096];
    __shared__ float maxs[4][48];

    const int tid = threadIdx.x, b = blockIdx.x;
    const int lane = tid & 63, wid = tid >> 6;
    const int i31 = lane & 31, h = lane >> 5;

    // ---- B-fragment loads (global, L2-resident): all 20 sets ----
    uint32_t Bv[20][4];
    const uint4* fg = (const uint4*)((const uint32_t*)wsf + WS_FRAG);
#pragma unroll
    for (int u = 0; u < 20; ++u) {
        uint4 t = fg[u * 64 + lane];
        Bv[u][0] = t.x; Bv[u][1] = t.y; Bv[u][2] = t.z; Bv[u][3] = t.w;
    }

    // ---- stage x: f16 2-split, packed-record layout ----
    const float* xb = x + (size_t)b * 4000;
#pragma unroll
    for (int it = 0; it < 2; ++it) {
        int u = tid + 256 * it;                     // pos-pair 0..499
        if (u < 500) {
            const int p0 = 2 * u;
            float v[4][2];
#pragma unroll
            for (int c = 0; c < 4; ++c) {
                float2 t = *(const float2*)(xb + c * 1000 + p0);
                v[c][0] = t.x; v[c][1] = t.y;
            }
#pragma unroll
            for (int e = 0; e < 2; ++e) {
                _Float16 a[4], r[4];
#pragma unroll
                for (int c = 0; c < 4; ++c) {
                    a[c] = (_Float16)v[c][e];
                    r[c] = (_Float16)(v[c][e] - (float)a[c]);
                }
                *(uint4*)&xls[4 * (p0 + e)] =
                    make_uint4(pkh(a[0], a[1]), pkh(a[2], a[3]),
                               pkh(r[0], r[1]), pkh(r[2], r[3]));
            }
        }
    }
    if (tid < 24) *(uint4*)&xls[4 * (1000 + tid)] = make_uint4(0, 0, 0, 0);
    __syncthreads();

    // ---- main loop: wave w owns tiles [8w, min(31, 8w+8)) ----
    float vmW[16], vmL[16];
#pragma unroll
    for (int e = 0; e < 16; ++e) { vmW[e] = -INFINITY; vmL[e] = -INFINITY; }

    const int t_beg = wid * 8;
    const int t_end = (wid == 3) ? 31 : (t_beg + 8);
    for (int tile = t_beg; tile < t_end; ++tile) {
        const int tb = tile * 32;
        f32x16 accW, accL;
#pragma unroll
        for (int e = 0; e < 16; ++e) { accW[e] = 0.f; accL[e] = 0.f; }
        const int Pb = tb + i31 + 2 * h;
#pragma unroll
        for (int s = 0; s < 5; ++s) {
            const int P = Pb + 4 * s;
            uint4 q0 = *(const uint4*)&xls[4 * P];
            uint4 q1 = *(const uint4*)&xls[4 * P + 4];
            f16x8 A1 = mkfrag(q0.x, q0.y, q1.x, q1.y);   // split0 @ P, P+1
            f16x8 A2 = mkfrag(q0.z, q0.w, q1.z, q1.w);   // split1 @ P, P+1
            f16x8 B0  = mkfrag(Bv[s][0],      Bv[s][1],      Bv[s][2],      Bv[s][3]);       // [w1s1|w2s1]
            f16x8 B1  = mkfrag(Bv[5+s][0],    Bv[5+s][1],    Bv[5+s][2],    Bv[5+s][3]);     // [w1s2|w2s2]
            f16x8 B2a = mkfrag(Bv[10+s][0],   Bv[10+s][1],   Bv[10+s][2],   Bv[10+s][3]);    // [Ls1|Ls2]
            f16x8 B2b = mkfrag(Bv[15+s][0],   Bv[15+s][1],   Bv[15+s][2],   Bv[15+s][3]);    // [Ls2|0]
            accW = __builtin_amdgcn_mfma_f32_32x32x16_f16(A1, B0,  accW, 0, 0, 0);
            accL = __builtin_amdgcn_mfma_f32_32x32x16_f16(A1, B2a, accL, 0, 0, 0);
            accW = __builtin_amdgcn_mfma_f32_32x32x16_f16(A1, B1,  accW, 0, 0, 0);
            accL = __builtin_amdgcn_mfma_f32_32x32x16_f16(A1, B2b, accL, 0, 0, 0);
            accW = __builtin_amdgcn_mfma_f32_32x32x16_f16(A2, B0,  accW, 0, 0, 0);
            accL = __builtin_amdgcn_mfma_f32_32x32x16_f16(A2, B2a, accL, 0, 0, 0);
        }
        if (tile < 30) {
#pragma unroll
            for (int e = 0; e < 16; ++e) {
                vmW[e] = fmaxf(vmW[e], accW[e]);
                vmL[e] = fmaxf(vmL[e], accL[e]);
            }
        } else {
#pragma unroll
            for (int e = 0; e < 16; ++e) {
                int row = (e & 3) + 8 * (e >> 2) + 4 * h;
                bool ok = (tb + row) < TVALID;
                vmW[e] = fmaxf(vmW[e], ok ? accW[e] : -INFINITY);
                vmL[e] = fmaxf(vmL[e], ok ? accL[e] : -INFINITY);
            }
        }
    }

    // per-wave reduce across acc slots + row-halves (lane^32); col = lane&31
    float mW = vmW[0], mL = vmL[0];
#pragma unroll
    for (int e = 1; e < 16; ++e) { mW = fmaxf(mW, vmW[e]); mL = fmaxf(mL, vmL[e]); }
    mW = fmaxf(mW, __shfl_xor(mW, 32, 64));
    mL = fmaxf(mL, __shfl_xor(mL, 32, 64));
    if (lane < 32) maxs[wid][lane] = mW;          // cols 0-15 = w1, 16-31 = w2
    if (lane < 16) maxs[wid][32 + lane] = mL;     // loc (valid cols 0-15 only)
    __syncthreads();

    // ---- epilogue: 16 lanes, one per motif (validated R2/R3 math) ----
    if (tid < 16) {
        const int m = tid;
        const float s_ = red[0];
        const float yb = y[b];
        float sc1 = fmaxf(fmaxf(maxs[0][m],      maxs[1][m]),
                          fmaxf(maxs[2][m],      maxs[3][m]));
        float sc2 = fmaxf(fmaxf(maxs[0][16 + m], maxs[1][16 + m]),
                          fmaxf(maxs[2][16 + m], maxs[3][16 + m]));
        float sc0 = fmaxf(fmaxf(maxs[0][32 + m], maxs[1][32 + m]),
                          fmaxf(maxs[2][32 + m], maxs[3][32 + m]));

        float p1 = 1.f / (1.f + expf(-sc1));
        float lp = logf(p1) + log1pf(-p1);
        float mx = lp;
#pragma unroll
        for (int o = 8; o; o >>= 1) mx = fmaxf(mx, __shfl_xor(mx, o, 16));
        float e = expf(lp - mx);
        float se_ = e;
#pragma unroll
        for (int o = 8; o; o >>= 1) se_ += __shfl_xor(se_, o, 16);
        float z = e / se_;
        float Aterm = z * logf(1e-20f + z);

        float p2 = 1.f / (1.f + expf(-sc2));
        float g0 = -logf(1e-16f + powf(1e-16f + p2, s_) + powf(1.0f - p2, s_));
        float Cterm = z * g0;
        float bterm = yb * fmaxf(logf(p2), -100.f)
                    + (1.f - yb) * fmaxf(logf(1.f - p2), -100.f);

        float AC = Aterm - Cterm;
#pragma unroll
        for (int o = 8; o; o >>= 1) AC += __shfl_xor(AC, o, 16);

        atomicAdd(&red[2 + m], z);
        atomicAdd(&red[18 + m], bterm);

        float p0 = 1.f / (1.f + expf(-sc0));
        float lp0 = logf(p0) + log1pf(-p0);
        float best = lp0; int bidx = m;
#pragma unroll
        for (int o = 8; o; o >>= 1) {
            float ov = __shfl_xor(best, o, 16);
            int   oi = __shfl_xor(bidx, o, 16);
            if (ov > best || (ov == best && oi < bidx)) { best = ov; bidx = oi; }
        }
        if (m == 0) {
            atomicAdd(&red[1], AC);
            float scb = fmaxf(fmaxf(maxs[0][32 + bidx], maxs[1][32 + bidx]),
                              fmaxf(maxs[2][32 + bidx], maxs[3][32 + bidx]));
            out[1 + b] = 1.f / (1.f + expf(-scb));
        }
    }
}

// ---------------- Kernel 3: KL + assemble loss ----------------
__global__ void finish_kernel(const float* __restrict__ qw_loc,
                              const float* __restrict__ qw_scale_raw,
                              const float* __restrict__ wsf,
                              float* __restrict__ out) {
    int tid = threadIdx.x;   // 64 threads
    double kl = 0.0;
    for (int i = tid; i < 1280; i += 64) {
        float loc = qw_loc[i], qs = softplus_f(qw_scale_raw[i]);
        float dl = loc + 0.01f;
        kl += (double)(logf(0.001f / qs) + (qs * qs + dl * dl) / 2e-6f - 0.5f);
    }
#pragma unroll
    for (int o = 32; o; o >>= 1) kl += __shfl_xor(kl, o, 64);
    if (tid == 0) {
        const float* red = wsf + WS_RED;
        float t = 0.f;
        for (int m = 0; m < 16; ++m) t += red[2 + m] * red[18 + m];
        float loss = red[1] / 4096.0f + (float)(2.0 * kl)
                   - red[0] * (t / (4096.0f * 4096.0f));
        out[0] = loss;
    }
}

extern "C" void kernel_launch(void* const* d_in, const int* in_sizes, int n_in,
                              void* d_out, int out_size, void* d_ws, size_t ws_size,
                              hipStream_t stream) {
    const float* x            = (const float*)d_in[0];
    const float* y            = (const float*)d_in[1];
    const float* qw_loc       = (const float*)d_in[2];
    const float* qw_scale_raw = (const float*)d_in[3];
    const float* gen_scale    = (const float*)d_in[4];
    const float* eps1         = (const float*)d_in[5];
    const float* eps2         = (const float*)d_in[6];
    float* out = (float*)d_out;
    float* wsf = (float*)d_ws;

    prep_kernel<<<5, 256, 0, stream>>>(qw_loc, qw_scale_raw, gen_scale, eps1, eps2, wsf);
    conv_kernel<<<B_N, 256, 0, stream>>>(x, y, wsf, wsf + WS_RED, out);
    finish_kernel<<<1, 64, 0, stream>>>(qw_loc, qw_scale_raw, wsf, out);
}

// Round 6
// 255.257 us; speedup vs baseline: 2.0951x; 1.0589x over previous
//
#include <hip/hip_runtime.h>
#include <math.h>

// Problem constants
#define B_N 4096
#define TVALID 981

typedef _Float16 f16x8 __attribute__((ext_vector_type(8)));
typedef float f32x16 __attribute__((ext_vector_type(16)));

// ws layout (dword offsets):
// [0, 3840): B fragments, 15 sets: set = grp*5 + s (s = k-step 0..4)
//   grp0=[w1|w2] (f16 single-split)  grp1=[Ls0|Ls1]  grp2=[Ls1|0]
//   dword idx = (set*64 + lane)*4 + q
// [3840): red block: [0]=s, [1]=S1, [2..18)=ZSUM, [18..34)=BSUM
#define WS_FRAG 0
#define WS_RED  3840

static __device__ __forceinline__ float softplus_f(float x) {
    // jax.nn.softplus = max(x,0) + log1p(exp(-|x|))
    return fmaxf(x, 0.f) + log1pf(expf(-fabsf(x)));
}
static __device__ __forceinline__ uint32_t pkh(_Float16 a, _Float16 b) {
    return (uint32_t)__builtin_bit_cast(unsigned short, a)
         | ((uint32_t)__builtin_bit_cast(unsigned short, b) << 16);
}
static __device__ __forceinline__ f16x8 mkfrag(uint32_t d0, uint32_t d1, uint32_t d2, uint32_t d3) {
    union { uint32_t u[4]; f16x8 v; } t;
    t.u[0] = d0; t.u[1] = d1; t.u[2] = d2; t.u[3] = d3;
    return t.v;
}

// ---------------- Kernel 1: B-fragment precompute + accum init ----------------
__global__ void prep_kernel(const float* __restrict__ qw_loc,
                            const float* __restrict__ qw_scale_raw,
                            const float* __restrict__ gen_scale,
                            const float* __restrict__ eps1,
                            const float* __restrict__ eps2,
                            float* __restrict__ wsf) {
    const int g = blockIdx.x * 256 + threadIdx.x;   // grid = 4*256 = 1024 >= 960
    float* red = wsf + WS_RED;
    if (g == 0) red[0] = 1.0f / softplus_f(gen_scale[0]);
    else if (g < 34) red[g] = 0.f;                  // S1 + 16 zsum + 16 bsum
    if (g >= 960) return;

    const int lane = g & 63, set = g >> 6;          // set 0..14
    const int grp = set / 5, s = set - grp * 5;
    const int h = lane >> 5, n = lane & 31, f = n & 15;
    int var, spl;                                    // var: 0=w1 1=w2 2=loc 3=zero
    if (grp == 0)      { var = (n < 16) ? 0 : 1; spl = 0; }
    else if (grp == 1) { var = 2;                spl = (n < 16) ? 0 : 1; }
    else               { var = (n < 16) ? 2 : 3; spl = 1; }

    uint32_t d[4];
#pragma unroll
    for (int q = 0; q < 4; ++q) {
        unsigned short es[2];
#pragma unroll
        for (int e = 0; e < 2; ++e) {
            const int j = 2 * q + e;                 // fragment element 0..7
            const int c = j & 3;
            const int kk = 4 * s + 2 * h + (j >> 2); // <= 19
            const int idx = f * 80 + c * 20 + kk;
            float w = 0.f;
            if (var != 3) {
                w = qw_loc[idx];
                if (var < 2) w += softplus_f(qw_scale_raw[idx]) * (var == 0 ? eps1[idx] : eps2[idx]);
            }
            _Float16 h1 = (_Float16)w;
            _Float16 hv = spl ? (_Float16)(w - (float)h1) : h1;
            es[e] = __builtin_bit_cast(unsigned short, hv);
        }
        d[q] = (uint32_t)es[0] | ((uint32_t)es[1] << 16);
    }
    uint4* out4 = (uint4*)((uint32_t*)wsf + WS_FRAG);
    out4[set * 64 + lane] = make_uint4(d[0], d[1], d[2], d[3]);
}

// ---------------- Kernel 2: dual-tile 32x32x16 f16 MFMA conv-max ----------------
__global__ __launch_bounds__(256) void conv_kernel(const float* __restrict__ x,
                                                   const float* __restrict__ y,
                                                   const float* __restrict__ wsf,
                                                   float* __restrict__ red,
                                                   float* __restrict__ out) {
    // packed per-position record: {c01 s0, c23 s0, c01 s1, c23 s1} = 16B, 1024 records
    __shared__ __align__(16) uint32_t xls[4096];
    __shared__ float maxs[4][48];

    const int tid = threadIdx.x, b = blockIdx.x;
    const int lane = tid & 63, wid = tid >> 6;
    const int i31 = lane & 31, h = lane >> 5;

    // ---- B-fragment loads (global, L2-resident): 15 sets ----
    uint32_t Bv[15][4];
    const uint4* fg = (const uint4*)((const uint32_t*)wsf + WS_FRAG);
#pragma unroll
    for (int u = 0; u < 15; ++u) {
        uint4 t = fg[u * 64 + lane];
        Bv[u][0] = t.x; Bv[u][1] = t.y; Bv[u][2] = t.z; Bv[u][3] = t.w;
    }

    // ---- stage x: f16 2-split, packed-record layout ----
    const float* xb = x + (size_t)b * 4000;
#pragma unroll
    for (int it = 0; it < 2; ++it) {
        int u = tid + 256 * it;                     // pos-pair 0..499
        if (u < 500) {
            const int p0 = 2 * u;
            float v[4][2];
#pragma unroll
            for (int c = 0; c < 4; ++c) {
                float2 t = *(const float2*)(xb + c * 1000 + p0);
                v[c][0] = t.x; v[c][1] = t.y;
            }
#pragma unroll
            for (int e = 0; e < 2; ++e) {
                _Float16 a[4], r[4];
#pragma unroll
                for (int c = 0; c < 4; ++c) {
                    a[c] = (_Float16)v[c][e];
                    r[c] = (_Float16)(v[c][e] - (float)a[c]);
                }
                *(uint4*)&xls[4 * (p0 + e)] =
                    make_uint4(pkh(a[0], a[1]), pkh(a[2], a[3]),
                               pkh(r[0], r[1]), pkh(r[2], r[3]));
            }
        }
    }
    if (tid < 24) *(uint4*)&xls[4 * (1000 + tid)] = make_uint4(0, 0, 0, 0);
    __syncthreads();

    // ---- main loop: wave w owns tiles 8w..8w+7 (wave3: 24..30), 2 tiles/iter ----
    float vmW[16], vmL[16];
#pragma unroll
    for (int e = 0; e < 16; ++e) { vmW[e] = -INFINITY; vmL[e] = -INFINITY; }

    for (int i = 0; i < 4; ++i) {
        const int t0 = wid * 8 + 2 * i;
        const int t1 = t0 + 1;
        const bool two = (t1 <= 30);                 // only t0==30 is single
        const int tba = t0 * 32, tbb = two ? t1 * 32 : tba;
        f32x16 accW0, accL0, accW1, accL1;
#pragma unroll
        for (int e = 0; e < 16; ++e) { accW0[e] = 0.f; accL0[e] = 0.f; accW1[e] = 0.f; accL1[e] = 0.f; }
        const int Pa0 = tba + i31 + 2 * h;
        const int Pb0 = tbb + i31 + 2 * h;
#pragma unroll
        for (int s = 0; s < 5; ++s) {
            const int Pa = Pa0 + 4 * s, Pb = Pb0 + 4 * s;
            uint4 qa0 = *(const uint4*)&xls[4 * Pa];
            uint4 qa1 = *(const uint4*)&xls[4 * Pa + 4];
            uint4 qb0 = *(const uint4*)&xls[4 * Pb];
            uint4 qb1 = *(const uint4*)&xls[4 * Pb + 4];
            f16x8 A1a = mkfrag(qa0.x, qa0.y, qa1.x, qa1.y);   // x split0
            f16x8 A2a = mkfrag(qa0.z, qa0.w, qa1.z, qa1.w);   // x split1
            f16x8 A1b = mkfrag(qb0.x, qb0.y, qb1.x, qb1.y);
            f16x8 A2b = mkfrag(qb0.z, qb0.w, qb1.z, qb1.w);
            f16x8 BW  = mkfrag(Bv[s][0],      Bv[s][1],      Bv[s][2],      Bv[s][3]);      // [w1|w2]
            f16x8 B2a = mkfrag(Bv[5 + s][0],  Bv[5 + s][1],  Bv[5 + s][2],  Bv[5 + s][3]);  // [Ls0|Ls1]
            f16x8 B2b = mkfrag(Bv[10 + s][0], Bv[10 + s][1], Bv[10 + s][2], Bv[10 + s][3]); // [Ls1|0]
            accW0 = __builtin_amdgcn_mfma_f32_32x32x16_f16(A1a, BW,  accW0, 0, 0, 0);
            accW1 = __builtin_amdgcn_mfma_f32_32x32x16_f16(A1b, BW,  accW1, 0, 0, 0);
            accL0 = __builtin_amdgcn_mfma_f32_32x32x16_f16(A1a, B2a, accL0, 0, 0, 0);
            accL1 = __builtin_amdgcn_mfma_f32_32x32x16_f16(A1b, B2a, accL1, 0, 0, 0);
            accL0 = __builtin_amdgcn_mfma_f32_32x32x16_f16(A2a, B2a, accL0, 0, 0, 0);
            accL1 = __builtin_amdgcn_mfma_f32_32x32x16_f16(A2b, B2a, accL1, 0, 0, 0);
            accL0 = __builtin_amdgcn_mfma_f32_32x32x16_f16(A1a, B2b, accL0, 0, 0, 0);
            accL1 = __builtin_amdgcn_mfma_f32_32x32x16_f16(A1b, B2b, accL1, 0, 0, 0);
        }
        if (t0 == 30) {                               // single tail tile, mask rows > 980
#pragma unroll
            for (int e = 0; e < 16; ++e) {
                int row = (e & 3) + 8 * (e >> 2) + 4 * h;
                bool ok = (960 + row) < TVALID;
                vmW[e] = fmaxf(vmW[e], ok ? accW0[e] : -INFINITY);
                vmL[e] = fmaxf(vmL[e], ok ? accL0[e] : -INFINITY);
            }
        } else {
#pragma unroll
            for (int e = 0; e < 16; ++e) {
                vmW[e] = fmaxf(fmaxf(vmW[e], accW0[e]), accW1[e]);
                vmL[e] = fmaxf(fmaxf(vmL[e], accL0[e]), accL1[e]);
            }
        }
    }

    // per-wave reduce across acc slots + row-halves (lane^32); col = lane&31
    float mW = vmW[0], mL = vmL[0];
#pragma unroll
    for (int e = 1; e < 16; ++e) { mW = fmaxf(mW, vmW[e]); mL = fmaxf(mL, vmL[e]); }
    mW = fmaxf(mW, __shfl_xor(mW, 32, 64));
    mL = fmaxf(mL, __shfl_xor(mL, 32, 64));
    if (lane < 32) maxs[wid][lane] = mW;          // cols 0-15 = w1, 16-31 = w2
    if (lane < 16) maxs[wid][32 + lane] = mL;     // loc
    __syncthreads();

    // ---- epilogue: 16 lanes, one per motif (validated R2-R4 math) ----
    if (tid < 16) {
        const int m = tid;
        const float s_ = red[0];
        const float yb = y[b];
        float sc1 = fmaxf(fmaxf(maxs[0][m],      maxs[1][m]),
                          fmaxf(maxs[2][m],      maxs[3][m]));
        float sc2 = fmaxf(fmaxf(maxs[0][16 + m], maxs[1][16 + m]),
                          fmaxf(maxs[2][16 + m], maxs[3][16 + m]));
        float sc0 = fmaxf(fmaxf(maxs[0][32 + m], maxs[1][32 + m]),
                          fmaxf(maxs[2][32 + m], maxs[3][32 + m]));

        float p1 = 1.f / (1.f + expf(-sc1));
        float lp = logf(p1) + log1pf(-p1);
        float mx = lp;
#pragma unroll
        for (int o = 8; o; o >>= 1) mx = fmaxf(mx, __shfl_xor(mx, o, 16));
        float e = expf(lp - mx);
        float se_ = e;
#pragma unroll
        for (int o = 8; o; o >>= 1) se_ += __shfl_xor(se_, o, 16);
        float z = e / se_;
        float Aterm = z * logf(1e-20f + z);

        float p2 = 1.f / (1.f + expf(-sc2));
        float g0 = -logf(1e-16f + powf(1e-16f + p2, s_) + powf(1.0f - p2, s_));
        float Cterm = z * g0;
        float bterm = yb * fmaxf(logf(p2), -100.f)
                    + (1.f - yb) * fmaxf(logf(1.f - p2), -100.f);

        float AC = Aterm - Cterm;
#pragma unroll
        for (int o = 8; o; o >>= 1) AC += __shfl_xor(AC, o, 16);

        atomicAdd(&red[2 + m], z);
        atomicAdd(&red[18 + m], bterm);

        float p0 = 1.f / (1.f + expf(-sc0));
        float lp0 = logf(p0) + log1pf(-p0);
        float best = lp0; int bidx = m;
#pragma unroll
        for (int o = 8; o; o >>= 1) {
            float ov = __shfl_xor(best, o, 16);
            int   oi = __shfl_xor(bidx, o, 16);
            if (ov > best || (ov == best && oi < bidx)) { best = ov; bidx = oi; }
        }
        if (m == 0) {
            atomicAdd(&red[1], AC);
            float scb = fmaxf(fmaxf(maxs[0][32 + bidx], maxs[1][32 + bidx]),
                              fmaxf(maxs[2][32 + bidx], maxs[3][32 + bidx]));
            out[1 + b] = 1.f / (1.f + expf(-scb));
        }
    }
}

// ---------------- Kernel 3: KL + assemble loss ----------------
__global__ void finish_kernel(const float* __restrict__ qw_loc,
                              const float* __restrict__ qw_scale_raw,
                              const float* __restrict__ wsf,
                              float* __restrict__ out) {
    int tid = threadIdx.x;   // 64 threads
    double kl = 0.0;
    for (int i = tid; i < 1280; i += 64) {
        float loc = qw_loc[i], qs = softplus_f(qw_scale_raw[i]);
        float dl = loc + 0.01f;
        kl += (double)(logf(0.001f / qs) + (qs * qs + dl * dl) / 2e-6f - 0.5f);
    }
#pragma unroll
    for (int o = 32; o; o >>= 1) kl += __shfl_xor(kl, o, 64);
    if (tid == 0) {
        const float* red = wsf + WS_RED;
        float t = 0.f;
        for (int m = 0; m < 16; ++m) t += red[2 + m] * red[18 + m];
        float loss = red[1] / 4096.0f + (float)(2.0 * kl)
                   - red[0] * (t / (4096.0f * 4096.0f));
        out[0] = loss;
    }
}

extern "C" void kernel_launch(void* const* d_in, const int* in_sizes, int n_in,
                              void* d_out, int out_size, void* d_ws, size_t ws_size,
                              hipStream_t stream) {
    const float* x            = (const float*)d_in[0];
    const float* y            = (const float*)d_in[1];
    const float* qw_loc       = (const float*)d_in[2];
    const float* qw_scale_raw = (const float*)d_in[3];
    const float* gen_scale    = (const float*)d_in[4];
    const float* eps1         = (const float*)d_in[5];
    const float* eps2         = (const float*)d_in[6];
    float* out = (float*)d_out;
    float* wsf = (float*)d_ws;

    prep_kernel<<<4, 256, 0, stream>>>(qw_loc, qw_scale_raw, gen_scale, eps1, eps2, wsf);
    conv_kernel<<<B_N, 256, 0, stream>>>(x, y, wsf, wsf + WS_RED, out);
    finish_kernel<<<1, 64, 0, stream>>>(qw_loc, qw_scale_raw, wsf, out);
}